// Round 13
// baseline (114.997 us; speedup 1.0000x reference)
//
#include <hip/hip_runtime.h>
#include <hip/hip_bf16.h>

// ---------- types ----------
typedef __attribute__((ext_vector_type(8))) short short8;
typedef __attribute__((ext_vector_type(4))) float f32x4;

__device__ __forceinline__ short tobf(float f) {
  __hip_bfloat16 h = __float2bfloat16(f);
  return *reinterpret_cast<short*>(&h);
}

// XOR swizzle of the 16B-column index within a 128B LDS row (G4 / T2).
__device__ __forceinline__ int swz(int row) { return (row ^ (row >> 3)) & 7; }

#define GLDS16(gp, lp) __builtin_amdgcn_global_load_lds( \
    (__attribute__((address_space(1))) void*)(gp),       \
    (__attribute__((address_space(3))) void*)(lp), 16, 0, 0)

// q pre-scale folded into QKV-GEMM epilogue: S = (q*alpha)·k is then in
// log2 domain with the 1/sqrt(64) attention scale included -> attn uses exp2.
#define QSCALE 0.18033688011112042f  // 0.125 * log2(e)

// ---------- fused prep kernel ----------
__global__ __launch_bounds__(256) void prep_k(
    const float* __restrict__ x, short* __restrict__ xb,
    const float* __restrict__ Wqkv, short* __restrict__ WqkvT,
    const float* __restrict__ Wout, short* __restrict__ WoutT,
    float* __restrict__ cost, float* __restrict__ sint) {
  __shared__ float t[64][65];
  const int bx = blockIdx.x, tid = threadIdx.x;
  if (bx < 1024) {
    int base = bx * 4096 + tid * 4;
#pragma unroll
    for (int rep = 0; rep < 4; ++rep) {
      int i = base + rep * 1024;
      float4 v = *(const float4*)(x + i);
      *(short4*)(xb + i) = make_short4(tobf(v.x), tobf(v.y), tobf(v.z), tobf(v.w));
    }
  } else if (bx < 1664) {
    const float* in;
    short* out;
    int C, bb;
    if (bx < 1408) { in = Wqkv; out = WqkvT; C = 1536; bb = bx - 1024; }
    else           { in = Wout; out = WoutT; C = 1024; bb = bx - 1408; }
    const int R = 1024;
    int nc = C >> 6;
    int br = bb / nc, bc = bb % nc;
    int lr = tid >> 6, lc = tid & 63;
#pragma unroll
    for (int j = 0; j < 16; ++j) {
      int r = j * 4 + lr;
      t[r][lc] = in[(size_t)(br * 64 + r) * C + bc * 64 + lc];
    }
    __syncthreads();
#pragma unroll
    for (int j = 0; j < 16; ++j) {
      int r = j * 4 + lr;
      out[(size_t)(bc * 64 + r) * R + br * 64 + lc] = tobf(t[lc][r]);
    }
  } else {
    int t2 = (bx - 1664) * 256 + tid;  // < 65536
    int s = t2 >> 5, f = t2 & 31;
    float inv = __expf(-(float)f * (logf(50000.0f) / 32.0f));
    float a = (float)s * inv;
    cost[t2] = cosf(a);
    sint[t2] = sinf(a);
  }
}

// ---------- GEMM: C[M][N] = A[M][K](bf16) * Bt[N][K](bf16)^T + bias ----------
// 128x64 tiles (BMxBN): QKV grid 768 = 3 blocks/CU exact, out-proj 512 = 2/CU.
// 4 waves, each owns 32x64 (acc[2][4]). MODE 0: RoPE + q-prescale epilogue,
// bf16 out. MODE 1: f32 out.
template <int MODE>
__global__ __launch_bounds__(256) void gemm_k(
    const short* __restrict__ A, const short* __restrict__ Bt,
    const float* __restrict__ bias, void* __restrict__ Cout,
    int M, int N, int K,
    const float* __restrict__ cost, const float* __restrict__ sint) {
  __shared__ short As[128 * 64];  // 16KB
  __shared__ short Bs[64 * 64];   // 8KB
  const int ntile = N >> 6;
  const int bm = blockIdx.x / ntile, bn = blockIdx.x % ntile;
  const int tid = threadIdx.x, w = tid >> 6, l = tid & 63;
  const int c = l & 15, g = l >> 4;
  const int m0 = bm * 128, n0 = bn * 64;

  f32x4 acc[2][4] = {};

  for (int k0 = 0; k0 < K; k0 += 64) {
#pragma unroll
    for (int j = 0; j < 4; ++j) {
      int rb = j * 32 + w * 8;
      int row = rb + (l >> 3);
      int colel = ((l & 7) ^ swz(row)) * 8;  // pre-swizzled source (rule #21)
      GLDS16(A + (size_t)(m0 + row) * K + k0 + colel, &As[rb * 64]);
      if (j < 2) GLDS16(Bt + (size_t)(n0 + row) * K + k0 + colel, &Bs[rb * 64]);
    }
    __syncthreads();
#pragma unroll
    for (int kk = 0; kk < 2; ++kk) {
      short8 af[2], bf[4];
#pragma unroll
      for (int mi = 0; mi < 2; ++mi) {
        int row = w * 32 + mi * 16 + c;
        af[mi] = *(const short8*)&As[row * 64 + ((kk * 4 + g) ^ swz(row)) * 8];
      }
#pragma unroll
      for (int ni = 0; ni < 4; ++ni) {
        int row = ni * 16 + c;
        bf[ni] = *(const short8*)&Bs[row * 64 + ((kk * 4 + g) ^ swz(row)) * 8];
      }
#pragma unroll
      for (int mi = 0; mi < 2; ++mi)
#pragma unroll
        for (int ni = 0; ni < 4; ++ni)
          acc[mi][ni] = __builtin_amdgcn_mfma_f32_16x16x32_bf16(af[mi], bf[ni], acc[mi][ni], 0, 0, 0);
    }
    __syncthreads();
  }

#pragma unroll
  for (int mi = 0; mi < 2; ++mi)
#pragma unroll
    for (int r = 0; r < 4; ++r) {
      int m = m0 + w * 32 + mi * 16 + g * 4 + r;
      int s = m & 2047;
#pragma unroll
      for (int ni = 0; ni < 4; ++ni) {
        int n = n0 + ni * 16 + c;
        float v = acc[mi][ni][r] + bias[n];
        if (MODE == 0) {
          if (n < 1280) {  // q or k region: apply RoPE
            int d = n & 63, f = d & 31;
            float cs = cost[s * 32 + f], sn = sint[s * 32 + f];
            float partner = acc[mi][ni ^ 2][r] + bias[n ^ 32];
            v = (d < 32) ? (v * cs - partner * sn) : (v * cs + partner * sn);
          }
          if (n < 1024) v *= QSCALE;  // q prescale (commutes with rotation)
          ((short*)Cout)[(size_t)m * N + n] = tobf(v);
        } else {
          ((float*)Cout)[(size_t)m * N + n] = v;
        }
      }
    }
}

// ---------- V transpose: qkv v-region -> vT[b*4+hg][64 d][2048 s] ----------
__global__ __launch_bounds__(256) void vtrans_k(const short* __restrict__ qkvb,
                                                short* __restrict__ vT) {
  __shared__ short t[64][68];
  const int bx = blockIdx.x;            // bg*32 + st
  const int st = bx & 31, bg = bx >> 5; // bg = b*4+hg
  const int b = bg >> 2, hg = bg & 3;
  const int tid = threadIdx.x, lr = tid >> 6, lc = tid & 63;
  const size_t inbase = (size_t)(b * 2048 + st * 64) * 1536 + 1280 + hg * 64;
#pragma unroll
  for (int jj = 0; jj < 16; ++jj) {
    int r = jj * 4 + lr;
    t[r][lc] = qkvb[inbase + (size_t)r * 1536 + lc];
  }
  __syncthreads();
  const size_t outbase = (size_t)(bg * 64) * 2048 + st * 64;
#pragma unroll
  for (int jj = 0; jj < 16; ++jj) {
    int d = jj * 4 + lr;
    vT[outbase + (size_t)d * 2048 + lc] = t[lc][d];
  }
}

// ---------- flash attention (causal, GQA) ----------
// QBLK=128: 4 waves x 32 q-rows (2 sets of 16) -> the same 16 K/V LDS
// fragment reads feed 32 MFMA (2x R12's LDS efficiency; LDS pipe was ~40%
// of the wall). Grid 512 = exactly 2 blocks/CU, balanced pairing (qt,15-qt)
// = 34 iters/CU. Triple-buffered GLDS K/V^T, prefetch distance 2, counted
// vmcnt(4) + raw s_barrier (never drain in-loop). NO-MAX log2-domain softmax.
__global__ __launch_bounds__(256) void attn_k(const short* __restrict__ qkv,
                                              const short* __restrict__ vT,
                                              short* __restrict__ aout) {
  __shared__ short Ks3[3][64 * 64];  // 24KB: K tiles (triple-buffered)
  __shared__ short Vt3[3][64 * 64];  // 24KB: V^T tiles
  __shared__ short Ps[4][16 * 64];   // 8KB: per-wave P tile (reused per set)

  const int bx = blockIdx.x;
  const int qt = (bx < 256) ? (15 - (bx >> 5)) : ((bx - 256) >> 5);
  const int bh = bx & 31;
  const int b = bh >> 4, h = bh & 15, hg = h >> 2;
  const int tid = threadIdx.x, w = tid >> 6, l = tid & 63;
  const int c = l & 15, g = l >> 4;
  const size_t rowbase = (size_t)(b * 2048) * 1536;

  // per-thread staging offsets (loop-invariant)
  const int i0row = w * 16 + (l >> 3);
  const int i1row = w * 16 + 8 + (l >> 3);
  const int c0 = ((l & 7) ^ swz(i0row)) * 8;
  const int c1 = ((l & 7) ^ swz(i1row)) * 8;
  const size_t k0off = (size_t)i0row * 1536 + c0;
  const size_t k1off = (size_t)i1row * 1536 + c1;
  const size_t v0off = (size_t)i0row * 2048 + c0;
  const size_t v1off = (size_t)i1row * 2048 + c1;
  const int lds0 = (w * 16) * 64;
  const int lds1 = (w * 16 + 8) * 64;
  const short* kbase = qkv + rowbase + 1024 + hg * 64;
  const short* vbase_p = vT + (size_t)((b * 4 + hg) * 64) * 2048;

  // Q fragments direct from global (one-time): q = qt*128 + w*32 + set*16 + c
  short8 aq[2][2];
#pragma unroll
  for (int set = 0; set < 2; ++set)
#pragma unroll
    for (int kk = 0; kk < 2; ++kk)
      aq[set][kk] = *(const short8*)(qkv + rowbase +
          (size_t)(qt * 128 + w * 32 + set * 16 + c) * 1536 + h * 64 + kk * 32 + g * 8);

  const int nkt = 2 * qt + 2;

  // ---- prologue: issue tiles 0 and 1 (nkt >= 2 always) ----
  GLDS16(kbase + k0off, &Ks3[0][lds0]);
  GLDS16(kbase + k1off, &Ks3[0][lds1]);
  GLDS16(vbase_p + v0off, &Vt3[0][lds0]);
  GLDS16(vbase_p + v1off, &Vt3[0][lds1]);
  GLDS16(kbase + 98304 + k0off, &Ks3[1][lds0]);
  GLDS16(kbase + 98304 + k1off, &Ks3[1][lds1]);
  GLDS16(vbase_p + 64 + v0off, &Vt3[1][lds0]);
  GLDS16(vbase_p + 64 + v1off, &Vt3[1][lds1]);
  asm volatile("s_waitcnt vmcnt(4)" ::: "memory");
  __builtin_amdgcn_s_barrier();
  __builtin_amdgcn_sched_barrier(0);

  f32x4 acco[2][4] = {};
  float lrun[2] = {0.f, 0.f};
  short* Pw = &Ps[w][0];
  int cur = 0, s2 = 2;
  const short* pk2 = kbase + 2 * 98304;
  const short* pv2 = vbase_p + 2 * 64;

  for (int j = 0; j < nkt; ++j) {
    const bool pf2 = (j + 2 < nkt);
    if (pf2) {  // issue tile j+2 (stays in flight across this iter's barrier)
      GLDS16(pk2 + k0off, &Ks3[s2][lds0]);
      GLDS16(pk2 + k1off, &Ks3[s2][lds1]);
      GLDS16(pv2 + v0off, &Vt3[s2][lds0]);
      GLDS16(pv2 + v1off, &Vt3[s2][lds1]);
    }

    // K fragment reads (shared by both q-sets)
    short8 bk[2][4];
#pragma unroll
    for (int kk = 0; kk < 2; ++kk)
#pragma unroll
      for (int nb = 0; nb < 4; ++nb) {
        int row = nb * 16 + c;
        bk[kk][nb] = *(const short8*)&Ks3[cur][row * 64 + ((kk * 4 + g) ^ swz(row)) * 8];
      }

    // QK both sets: S^T = K * Q^T, lane (c,g) holds S[q][k=nb*16+g*4+r]
    f32x4 sfr[2][4] = {};
    __builtin_amdgcn_s_setprio(1);
#pragma unroll
    for (int set = 0; set < 2; ++set)
#pragma unroll
      for (int kk = 0; kk < 2; ++kk)
#pragma unroll
        for (int nb = 0; nb < 4; ++nb)
          sfr[set][nb] = __builtin_amdgcn_mfma_f32_16x16x32_bf16(
              bk[kk][nb], aq[set][kk], sfr[set][nb], 0, 0, 0);
    __builtin_amdgcn_s_setprio(0);

    // V fragment reads (bk now dead)
    short8 bv[2][4];
#pragma unroll
    for (int kk = 0; kk < 2; ++kk)
#pragma unroll
      for (int nb = 0; nb < 4; ++nb) {
        int row = nb * 16 + c;
        bv[kk][nb] = *(const short8*)&Vt3[cur][row * 64 + ((kk * 4 + g) ^ swz(row)) * 8];
      }

    // causal mask: only the last two k-tiles intersect the diagonal band
    if (j >= 2 * qt) {
#pragma unroll
      for (int set = 0; set < 2; ++set) {
        int qg = qt * 128 + w * 32 + set * 16 + c;
#pragma unroll
        for (int nb = 0; nb < 4; ++nb)
#pragma unroll
          for (int r = 0; r < 4; ++r)
            if (j * 64 + nb * 16 + g * 4 + r > qg) sfr[set][nb][r] = -1e30f;
      }
    }

    // per set: NO-MAX softmax (log2 domain), P bounce, PV
#pragma unroll
    for (int set = 0; set < 2; ++set) {
      float rs = 0.f;
#pragma unroll
      for (int nb = 0; nb < 4; ++nb)
#pragma unroll
        for (int r = 0; r < 4; ++r) {
          float p = exp2f(sfr[set][nb][r]);
          sfr[set][nb][r] = p;
          rs += p;
        }
      rs += __shfl_xor(rs, 16, 64);
      rs += __shfl_xor(rs, 32, 64);
      lrun[set] += rs;

      // P -> wave-private LDS (same-wave in-order DS: safe to reuse per set)
#pragma unroll
      for (int nb = 0; nb < 4; ++nb) {
        short4 pv;
        pv.x = tobf(sfr[set][nb][0]);
        pv.y = tobf(sfr[set][nb][1]);
        pv.z = tobf(sfr[set][nb][2]);
        pv.w = tobf(sfr[set][nb][3]);
        int pslot = (nb * 2 + (g >> 1)) ^ swz(c);
        *(short4*)&Pw[c * 64 + pslot * 8 + (g & 1) * 4] = pv;
      }

      __builtin_amdgcn_s_setprio(1);
#pragma unroll
      for (int kk = 0; kk < 2; ++kk) {
        short8 ap = *(const short8*)&Pw[c * 64 + (((kk * 4 + g) ^ swz(c)) * 8)];
#pragma unroll
        for (int nb = 0; nb < 4; ++nb)
          acco[set][nb] = __builtin_amdgcn_mfma_f32_16x16x32_bf16(ap, bv[kk][nb], acco[set][nb], 0, 0, 0);
      }
      __builtin_amdgcn_s_setprio(0);
    }

    // counted-vmcnt barrier (T4): tile j+1 landed, tile j+2 stays in flight
    if (pf2) asm volatile("s_waitcnt vmcnt(4)" ::: "memory");
    else     asm volatile("s_waitcnt vmcnt(0)" ::: "memory");
    __builtin_amdgcn_s_barrier();
    __builtin_amdgcn_sched_barrier(0);

    cur = (cur == 2) ? 0 : cur + 1;
    s2 = (s2 == 2) ? 0 : s2 + 1;
    pk2 += 98304;
    pv2 += 64;
  }

  // epilogue: broadcast 1/l to acco row layout, store bf16
#pragma unroll
  for (int set = 0; set < 2; ++set) {
    float li = 1.0f / lrun[set];
    float lb[4];
#pragma unroll
    for (int r = 0; r < 4; ++r) lb[r] = __shfl(li, g * 4 + r, 64);
#pragma unroll
    for (int nb = 0; nb < 4; ++nb)
#pragma unroll
      for (int r = 0; r < 4; ++r) {
        int m = b * 2048 + qt * 128 + w * 32 + set * 16 + g * 4 + r;
        int n = h * 64 + nb * 16 + c;
        aout[(size_t)m * 1024 + n] = tobf(acco[set][nb][r] * lb[r]);
      }
  }
}

// ---------- launch ----------
extern "C" void kernel_launch(void* const* d_in, const int* in_sizes, int n_in,
                              void* d_out, int out_size, void* d_ws, size_t ws_size,
                              hipStream_t stream) {
  const float* x    = (const float*)d_in[0];
  const float* Wqkv = (const float*)d_in[1];
  const float* bqkv = (const float*)d_in[2];
  const float* Wout = (const float*)d_in[3];
  const float* bout = (const float*)d_in[4];

  char* ws = (char*)d_ws;
  short* xb    = (short*)ws; ws += 8388608;    // x bf16 [4096][1024]
  short* WqkvT = (short*)ws; ws += 3145728;    // [1536][1024] bf16
  short* WoutT = (short*)ws; ws += 2097152;    // [1024][1024] bf16
  short* qkvb  = (short*)ws; ws += 12582912;   // [4096][1536] bf16 (post-RoPE)
  short* attnb = (short*)ws; ws += 8388608;    // [4096][1024] bf16
  short* vTb   = (short*)ws; ws += 2097152;    // [8][64][2048] bf16 (V transposed)
  float* cost  = (float*)ws; ws += 262144;     // [2048][32]
  float* sint  = (float*)ws; ws += 262144;

  prep_k<<<1920, 256, 0, stream>>>(x, xb, Wqkv, WqkvT, Wout, WoutT, cost, sint);
  gemm_k<0><<<768, 256, 0, stream>>>(xb, WqkvT, bqkv, (void*)qkvb, 4096, 1536, 1024, cost, sint);
  vtrans_k<<<256, 256, 0, stream>>>(qkvb, vTb);
  attn_k<<<512, 256, 0, stream>>>(qkvb, vTb, attnb);
  gemm_k<1><<<512, 256, 0, stream>>>(attnb, WoutT, bout, d_out, 4096, 1024, 1024, cost, sint);
}

// Round 14
// 109.322 us; speedup vs baseline: 1.0519x; 1.0519x over previous
//
#include <hip/hip_runtime.h>
#include <hip/hip_bf16.h>

// ---------- types ----------
typedef __attribute__((ext_vector_type(8))) short short8;
typedef __attribute__((ext_vector_type(4))) float f32x4;

__device__ __forceinline__ short tobf(float f) {
  __hip_bfloat16 h = __float2bfloat16(f);
  return *reinterpret_cast<short*>(&h);
}
__device__ __forceinline__ float frombf(short s) {
  unsigned u = ((unsigned)(unsigned short)s) << 16;
  return __uint_as_float(u);
}

// XOR swizzle of the 16B-column index within a 128B LDS row (G4 / T2).
__device__ __forceinline__ int swz(int row) { return (row ^ (row >> 3)) & 7; }

#define GLDS16(gp, lp) __builtin_amdgcn_global_load_lds( \
    (__attribute__((address_space(1))) void*)(gp),       \
    (__attribute__((address_space(3))) void*)(lp), 16, 0, 0)

// q pre-scale folded into QKV-GEMM epilogue: S = (q*alpha)·k is then in
// log2 domain with the 1/sqrt(64) attention scale included -> attn uses exp2.
#define QSCALE 0.18033688011112042f  // 0.125 * log2(e)

// ---------- fused prep kernel ----------
__global__ __launch_bounds__(256) void prep_k(
    const float* __restrict__ x, short* __restrict__ xb,
    const float* __restrict__ Wqkv, short* __restrict__ WqkvT,
    const float* __restrict__ Wout, short* __restrict__ WoutT,
    float* __restrict__ cost, float* __restrict__ sint) {
  __shared__ float t[64][65];
  const int bx = blockIdx.x, tid = threadIdx.x;
  if (bx < 1024) {
    int base = bx * 4096 + tid * 4;
#pragma unroll
    for (int rep = 0; rep < 4; ++rep) {
      int i = base + rep * 1024;
      float4 v = *(const float4*)(x + i);
      *(short4*)(xb + i) = make_short4(tobf(v.x), tobf(v.y), tobf(v.z), tobf(v.w));
    }
  } else if (bx < 1664) {
    const float* in;
    short* out;
    int C, bb;
    if (bx < 1408) { in = Wqkv; out = WqkvT; C = 1536; bb = bx - 1024; }
    else           { in = Wout; out = WoutT; C = 1024; bb = bx - 1408; }
    const int R = 1024;
    int nc = C >> 6;
    int br = bb / nc, bc = bb % nc;
    int lr = tid >> 6, lc = tid & 63;
#pragma unroll
    for (int j = 0; j < 16; ++j) {
      int r = j * 4 + lr;
      t[r][lc] = in[(size_t)(br * 64 + r) * C + bc * 64 + lc];
    }
    __syncthreads();
#pragma unroll
    for (int j = 0; j < 16; ++j) {
      int r = j * 4 + lr;
      out[(size_t)(bc * 64 + r) * R + br * 64 + lc] = tobf(t[lc][r]);
    }
  } else {
    int t2 = (bx - 1664) * 256 + tid;  // < 65536
    int s = t2 >> 5, f = t2 & 31;
    float inv = __expf(-(float)f * (logf(50000.0f) / 32.0f));
    float a = (float)s * inv;
    cost[t2] = cosf(a);
    sint[t2] = sinf(a);
  }
}

// ---------- GEMM: C[M][N] = A[M][K](bf16) * Bt[N][K](bf16)^T + bias ----------
template <int MODE>
__global__ __launch_bounds__(256) void gemm_k(
    const short* __restrict__ A, const short* __restrict__ Bt,
    const float* __restrict__ bias, void* __restrict__ Cout,
    int M, int N, int K,
    const float* __restrict__ cost, const float* __restrict__ sint) {
  __shared__ short As[128 * 64];  // 16KB
  __shared__ short Bs[64 * 64];   // 8KB
  const int ntile = N >> 6;
  const int bm = blockIdx.x / ntile, bn = blockIdx.x % ntile;
  const int tid = threadIdx.x, w = tid >> 6, l = tid & 63;
  const int c = l & 15, g = l >> 4;
  const int m0 = bm * 128, n0 = bn * 64;

  f32x4 acc[2][4] = {};

  for (int k0 = 0; k0 < K; k0 += 64) {
#pragma unroll
    for (int j = 0; j < 4; ++j) {
      int rb = j * 32 + w * 8;
      int row = rb + (l >> 3);
      int colel = ((l & 7) ^ swz(row)) * 8;  // pre-swizzled source (rule #21)
      GLDS16(A + (size_t)(m0 + row) * K + k0 + colel, &As[rb * 64]);
      if (j < 2) GLDS16(Bt + (size_t)(n0 + row) * K + k0 + colel, &Bs[rb * 64]);
    }
    __syncthreads();
#pragma unroll
    for (int kk = 0; kk < 2; ++kk) {
      short8 af[2], bf[4];
#pragma unroll
      for (int mi = 0; mi < 2; ++mi) {
        int row = w * 32 + mi * 16 + c;
        af[mi] = *(const short8*)&As[row * 64 + ((kk * 4 + g) ^ swz(row)) * 8];
      }
#pragma unroll
      for (int ni = 0; ni < 4; ++ni) {
        int row = ni * 16 + c;
        bf[ni] = *(const short8*)&Bs[row * 64 + ((kk * 4 + g) ^ swz(row)) * 8];
      }
#pragma unroll
      for (int mi = 0; mi < 2; ++mi)
#pragma unroll
        for (int ni = 0; ni < 4; ++ni)
          acc[mi][ni] = __builtin_amdgcn_mfma_f32_16x16x32_bf16(af[mi], bf[ni], acc[mi][ni], 0, 0, 0);
    }
    __syncthreads();
  }

#pragma unroll
  for (int mi = 0; mi < 2; ++mi)
#pragma unroll
    for (int r = 0; r < 4; ++r) {
      int m = m0 + w * 32 + mi * 16 + g * 4 + r;
      int s = m & 2047;
#pragma unroll
      for (int ni = 0; ni < 4; ++ni) {
        int n = n0 + ni * 16 + c;
        float v = acc[mi][ni][r] + bias[n];
        if (MODE == 0) {
          if (n < 1280) {  // q or k region: apply RoPE
            int d = n & 63, f = d & 31;
            float cs = cost[s * 32 + f], sn = sint[s * 32 + f];
            float partner = acc[mi][ni ^ 2][r] + bias[n ^ 32];
            v = (d < 32) ? (v * cs - partner * sn) : (v * cs + partner * sn);
          }
          if (n < 1024) v *= QSCALE;  // q prescale (commutes with rotation)
          ((short*)Cout)[(size_t)m * N + n] = tobf(v);
        } else {
          ((float*)Cout)[(size_t)m * N + n] = v;
        }
      }
    }
}

// ---------- V transpose: qkv v-region -> vT[b*4+hg][64 d][2048 s] ----------
__global__ __launch_bounds__(256) void vtrans_k(const short* __restrict__ qkvb,
                                                short* __restrict__ vT) {
  __shared__ short t[64][68];
  const int bx = blockIdx.x;            // bg*32 + st
  const int st = bx & 31, bg = bx >> 5; // bg = b*4+hg
  const int b = bg >> 2, hg = bg & 3;
  const int tid = threadIdx.x, lr = tid >> 6, lc = tid & 63;
  const size_t inbase = (size_t)(b * 2048 + st * 64) * 1536 + 1280 + hg * 64;
#pragma unroll
  for (int jj = 0; jj < 16; ++jj) {
    int r = jj * 4 + lr;
    t[r][lc] = qkvb[inbase + (size_t)r * 1536 + lc];
  }
  __syncthreads();
  const size_t outbase = (size_t)(bg * 64) * 2048 + st * 64;
#pragma unroll
  for (int jj = 0; jj < 16; ++jj) {
    int d = jj * 4 + lr;
    vT[outbase + (size_t)d * 2048 + lc] = t[lc][d];
  }
}

// ---------- flash attention (causal, GQA), SPLIT-K uniform blocks ----------
// Each q-tile's (QBLK=128) k-range splits into two equal halves (qt+1 tiles).
// Block (bh, p, half) processes q-tile 15-p's half (16-p iters) then q-tile
// p's half (p+1 iters) -> EVERY block = exactly 17 iters, grid 512 = 2
// equal-length blocks/CU, 2 waves/SIMD with no tail (fix for the solo-wave
// latency exposure measured in R13: occ 13%, 4650 cyc/iter vs ~1000 work).
// No-max softmax makes halves combine by pure addition (combine_k).
// Pipeline: triple-buffered GLDS K/V^T, distance-2 prefetch, counted
// vmcnt(4) + raw s_barrier. Partials: bf16 acco sums + f32 lrun.
__global__ __launch_bounds__(256) void attn_k(const short* __restrict__ qkv,
                                              const short* __restrict__ vT,
                                              short* __restrict__ pacc,
                                              float* __restrict__ plrun) {
  __shared__ short Ks3[3][64 * 64];  // 24KB
  __shared__ short Vt3[3][64 * 64];  // 24KB
  __shared__ short Ps[4][16 * 64];   // 8KB per-wave P tile

  const int bx = blockIdx.x;
  const int bh = bx & 31;
  const int prr = bx >> 5;           // 0..15
  const int half = prr >> 3;         // 0 or 1
  const int p = prr & 7;             // 0..7
  const int qtB = 15 - p;            // long part first: sB = 16-p (>= 9)
  const int qtA = p;                 // short part: sA = p+1
  const int sB = 16 - p;
  const int kB0 = half * (qtB + 1);
  const int kA0 = half * (qtA + 1);
  const int b = bh >> 4, h = bh & 15, hg = h >> 2;
  const int tid = threadIdx.x, w = tid >> 6, l = tid & 63;
  const int c = l & 15, g = l >> 4;
  const size_t rowbase = (size_t)(b * 2048) * 1536;

  // per-thread staging offsets (loop-invariant)
  const int i0row = w * 16 + (l >> 3);
  const int i1row = w * 16 + 8 + (l >> 3);
  const int c0 = ((l & 7) ^ swz(i0row)) * 8;
  const int c1 = ((l & 7) ^ swz(i1row)) * 8;
  const size_t k0off = (size_t)i0row * 1536 + c0;
  const size_t k1off = (size_t)i1row * 1536 + c1;
  const size_t v0off = (size_t)i0row * 2048 + c0;
  const size_t v1off = (size_t)i1row * 2048 + c1;
  const int lds0 = (w * 16) * 64;
  const int lds1 = (w * 16 + 8) * 64;
  const short* kbase = qkv + rowbase + 1024 + hg * 64;
  const short* vbase_p = vT + (size_t)((b * 4 + hg) * 64) * 2048;

  // Q fragments for both parts (one-time, direct global)
  short8 aqB[2][2], aqA[2][2];
#pragma unroll
  for (int set = 0; set < 2; ++set)
#pragma unroll
    for (int kk = 0; kk < 2; ++kk) {
      aqB[set][kk] = *(const short8*)(qkv + rowbase +
          (size_t)(qtB * 128 + w * 32 + set * 16 + c) * 1536 + h * 64 + kk * 32 + g * 8);
      aqA[set][kk] = *(const short8*)(qkv + rowbase +
          (size_t)(qtA * 128 + w * 32 + set * 16 + c) * 1536 + h * 64 + kk * 32 + g * 8);
    }

#define KT(i) (((i) < sB) ? (kB0 + (i)) : (kA0 + ((i) - sB)))

  // ---- prologue: issue tiles KT(0), KT(1)  (sB >= 9 so both in part B) ----
  {
    int t0 = KT(0), t1 = KT(1);
    GLDS16(kbase + (size_t)t0 * 98304 + k0off, &Ks3[0][lds0]);
    GLDS16(kbase + (size_t)t0 * 98304 + k1off, &Ks3[0][lds1]);
    GLDS16(vbase_p + t0 * 64 + v0off, &Vt3[0][lds0]);
    GLDS16(vbase_p + t0 * 64 + v1off, &Vt3[0][lds1]);
    GLDS16(kbase + (size_t)t1 * 98304 + k0off, &Ks3[1][lds0]);
    GLDS16(kbase + (size_t)t1 * 98304 + k1off, &Ks3[1][lds1]);
    GLDS16(vbase_p + t1 * 64 + v0off, &Vt3[1][lds0]);
    GLDS16(vbase_p + t1 * 64 + v1off, &Vt3[1][lds1]);
  }
  asm volatile("s_waitcnt vmcnt(4)" ::: "memory");
  __builtin_amdgcn_s_barrier();
  __builtin_amdgcn_sched_barrier(0);

  f32x4 acco[2][4] = {};
  float lrun[2] = {0.f, 0.f};
  short* Pw = &Ps[w][0];
  int cur = 0, s2 = 2;

#define ITER(qtc, aqc)                                                          \
  {                                                                             \
    const int kt = KT(i);                                                       \
    const bool pf2 = (i + 2 < 17);                                              \
    if (pf2) {                                                                  \
      int ktp = KT(i + 2);                                                      \
      GLDS16(kbase + (size_t)ktp * 98304 + k0off, &Ks3[s2][lds0]);              \
      GLDS16(kbase + (size_t)ktp * 98304 + k1off, &Ks3[s2][lds1]);              \
      GLDS16(vbase_p + ktp * 64 + v0off, &Vt3[s2][lds0]);                       \
      GLDS16(vbase_p + ktp * 64 + v1off, &Vt3[s2][lds1]);                       \
    }                                                                           \
    short8 bk[2][4];                                                            \
    _Pragma("unroll") for (int kk = 0; kk < 2; ++kk)                            \
      _Pragma("unroll") for (int nb = 0; nb < 4; ++nb) {                        \
        int row = nb * 16 + c;                                                  \
        bk[kk][nb] = *(const short8*)&Ks3[cur][row * 64 + ((kk * 4 + g) ^ swz(row)) * 8]; \
      }                                                                         \
    f32x4 sfr[2][4] = {};                                                       \
    __builtin_amdgcn_s_setprio(1);                                              \
    _Pragma("unroll") for (int set = 0; set < 2; ++set)                         \
      _Pragma("unroll") for (int kk = 0; kk < 2; ++kk)                          \
        _Pragma("unroll") for (int nb = 0; nb < 4; ++nb)                        \
          sfr[set][nb] = __builtin_amdgcn_mfma_f32_16x16x32_bf16(               \
              bk[kk][nb], aqc[set][kk], sfr[set][nb], 0, 0, 0);                 \
    __builtin_amdgcn_s_setprio(0);                                              \
    short8 bv[2][4];                                                            \
    _Pragma("unroll") for (int kk = 0; kk < 2; ++kk)                            \
      _Pragma("unroll") for (int nb = 0; nb < 4; ++nb) {                        \
        int row = nb * 16 + c;                                                  \
        bv[kk][nb] = *(const short8*)&Vt3[cur][row * 64 + ((kk * 4 + g) ^ swz(row)) * 8]; \
      }                                                                         \
    if (kt >= 2 * (qtc)) {                                                      \
      _Pragma("unroll") for (int set = 0; set < 2; ++set) {                     \
        int qg = (qtc)*128 + w * 32 + set * 16 + c;                             \
        _Pragma("unroll") for (int nb = 0; nb < 4; ++nb)                        \
          _Pragma("unroll") for (int r = 0; r < 4; ++r)                         \
            if (kt * 64 + nb * 16 + g * 4 + r > qg) sfr[set][nb][r] = -1e30f;   \
      }                                                                         \
    }                                                                           \
    _Pragma("unroll") for (int set = 0; set < 2; ++set) {                       \
      float rs = 0.f;                                                           \
      _Pragma("unroll") for (int nb = 0; nb < 4; ++nb)                          \
        _Pragma("unroll") for (int r = 0; r < 4; ++r) {                         \
          float pv_ = exp2f(sfr[set][nb][r]);                                   \
          sfr[set][nb][r] = pv_;                                                \
          rs += pv_;                                                            \
        }                                                                       \
      rs += __shfl_xor(rs, 16, 64);                                             \
      rs += __shfl_xor(rs, 32, 64);                                             \
      lrun[set] += rs;                                                          \
      _Pragma("unroll") for (int nb = 0; nb < 4; ++nb) {                        \
        short4 pq;                                                              \
        pq.x = tobf(sfr[set][nb][0]);                                           \
        pq.y = tobf(sfr[set][nb][1]);                                           \
        pq.z = tobf(sfr[set][nb][2]);                                           \
        pq.w = tobf(sfr[set][nb][3]);                                           \
        int pslot = (nb * 2 + (g >> 1)) ^ swz(c);                               \
        *(short4*)&Pw[c * 64 + pslot * 8 + (g & 1) * 4] = pq;                   \
      }                                                                         \
      __builtin_amdgcn_s_setprio(1);                                            \
      _Pragma("unroll") for (int kk = 0; kk < 2; ++kk) {                        \
        short8 ap = *(const short8*)&Pw[c * 64 + (((kk * 4 + g) ^ swz(c)) * 8)];\
        _Pragma("unroll") for (int nb = 0; nb < 4; ++nb)                        \
          acco[set][nb] = __builtin_amdgcn_mfma_f32_16x16x32_bf16(              \
              ap, bv[kk][nb], acco[set][nb], 0, 0, 0);                          \
      }                                                                         \
      __builtin_amdgcn_s_setprio(0);                                            \
    }                                                                           \
    if (pf2) asm volatile("s_waitcnt vmcnt(4)" ::: "memory");                   \
    else     asm volatile("s_waitcnt vmcnt(0)" ::: "memory");                   \
    __builtin_amdgcn_s_barrier();                                               \
    __builtin_amdgcn_sched_barrier(0);                                          \
    cur = (cur == 2) ? 0 : cur + 1;                                             \
    s2 = (s2 == 2) ? 0 : s2 + 1;                                                \
  }

#define STORE_PARTIAL(qtP)                                                      \
  {                                                                             \
    size_t pb = ((size_t)((bh * 16 + (qtP)) * 2 + half)) * 8192;                \
    _Pragma("unroll") for (int set = 0; set < 2; ++set) {                       \
      _Pragma("unroll") for (int nb = 0; nb < 4; ++nb)                          \
        _Pragma("unroll") for (int r = 0; r < 4; ++r) {                         \
          int row = w * 32 + set * 16 + g * 4 + r;                              \
          pacc[pb + row * 64 + nb * 16 + c] = tobf(acco[set][nb][r]);           \
          acco[set][nb][r] = 0.f;                                               \
        }                                                                       \
      if (g == 0)                                                               \
        plrun[((bh * 16 + (qtP)) * 2 + half) * 128 + w * 32 + set * 16 + c] = lrun[set]; \
      lrun[set] = 0.f;                                                          \
    }                                                                           \
  }

  int i = 0;
  for (; i < sB; ++i) ITER(qtB, aqB);
  STORE_PARTIAL(qtB);
  for (; i < 17; ++i) ITER(qtA, aqA);
  STORE_PARTIAL(qtA);

#undef ITER
#undef STORE_PARTIAL
#undef KT
}

// ---------- combine: attnb = (pacc[h0] + pacc[h1]) / (lrun[h0] + lrun[h1]) ----------
__global__ __launch_bounds__(256) void combine_k(const short* __restrict__ pacc,
                                                 const float* __restrict__ plrun,
                                                 short* __restrict__ attnb) {
  int e = blockIdx.x * 256 + threadIdx.x;  // 0..524287
  int d8 = e & 7;
  int t = e >> 3;
  int row = t & 127;
  int t2 = t >> 7;
  int qt = t2 & 15;
  int bh = t2 >> 4;
  size_t pb = (size_t)((bh * 16 + qt) * 2) * 8192 + row * 64 + d8 * 8;
  short8 a0 = *(const short8*)(pacc + pb);
  short8 a1 = *(const short8*)(pacc + pb + 8192);
  float l = plrun[(bh * 16 + qt) * 2 * 128 + row] +
            plrun[((bh * 16 + qt) * 2 + 1) * 128 + row];
  float li = 1.0f / l;
  int b = bh >> 4, h = bh & 15;
  int m = b * 2048 + qt * 128 + row;
  int n = h * 64 + d8 * 8;
  short8 o;
#pragma unroll
  for (int k = 0; k < 8; ++k) o[k] = tobf((frombf(a0[k]) + frombf(a1[k])) * li);
  *(short8*)(attnb + (size_t)m * 1024 + n) = o;
}

// ---------- launch ----------
extern "C" void kernel_launch(void* const* d_in, const int* in_sizes, int n_in,
                              void* d_out, int out_size, void* d_ws, size_t ws_size,
                              hipStream_t stream) {
  const float* x    = (const float*)d_in[0];
  const float* Wqkv = (const float*)d_in[1];
  const float* bqkv = (const float*)d_in[2];
  const float* Wout = (const float*)d_in[3];
  const float* bout = (const float*)d_in[4];

  char* ws = (char*)d_ws;
  short* xb    = (short*)ws; ws += 8388608;    // x bf16 [4096][1024]
  short* WqkvT = (short*)ws; ws += 3145728;    // [1536][1024] bf16
  short* WoutT = (short*)ws; ws += 2097152;    // [1024][1024] bf16
  short* qkvb  = (short*)ws; ws += 12582912;   // [4096][1536] bf16 (post-RoPE)
  short* attnb = (short*)ws; ws += 8388608;    // [4096][1024] bf16
  short* vTb   = (short*)ws; ws += 2097152;    // [8][64][2048] bf16 (V transposed)
  float* cost  = (float*)ws; ws += 262144;     // [2048][32]
  float* sint  = (float*)ws; ws += 262144;
  short* pacc  = (short*)ws; ws += 16777216;   // [32][16][2][128][64] bf16 partial acco
  float* plrun = (float*)ws; ws += 524288;     // [32][16][2][128] f32 partial lrun

  prep_k<<<1920, 256, 0, stream>>>(x, xb, Wqkv, WqkvT, Wout, WoutT, cost, sint);
  gemm_k<0><<<768, 256, 0, stream>>>(xb, WqkvT, bqkv, (void*)qkvb, 4096, 1536, 1024, cost, sint);
  vtrans_k<<<256, 256, 0, stream>>>(qkvb, vTb);
  attn_k<<<512, 256, 0, stream>>>(qkvb, vTb, pacc, plrun);
  combine_k<<<2048, 256, 0, stream>>>(pacc, plrun, attnb);
  gemm_k<1><<<512, 256, 0, stream>>>(attnb, WoutT, bout, d_out, 4096, 1024, 1024, cost, sint);
}

// Round 16
// 101.953 us; speedup vs baseline: 1.1279x; 1.0723x over previous
//
#include <hip/hip_runtime.h>
#include <hip/hip_bf16.h>

// ---------- types ----------
typedef __attribute__((ext_vector_type(8))) short short8;
typedef __attribute__((ext_vector_type(4))) float f32x4;

__device__ __forceinline__ short tobf(float f) {
  __hip_bfloat16 h = __float2bfloat16(f);
  return *reinterpret_cast<short*>(&h);
}
__device__ __forceinline__ float frombf(short s) {
  unsigned u = ((unsigned)(unsigned short)s) << 16;
  return __uint_as_float(u);
}

// XOR swizzle of the 16B-column index within a 128B LDS row (G4 / T2).
__device__ __forceinline__ int swz(int row) { return (row ^ (row >> 3)) & 7; }

#define GLDS16(gp, lp) __builtin_amdgcn_global_load_lds( \
    (__attribute__((address_space(1))) void*)(gp),       \
    (__attribute__((address_space(3))) void*)(lp), 16, 0, 0)

// q pre-scale folded into QKV-GEMM epilogue: S = (q*alpha)·k is then in
// log2 domain with the 1/sqrt(64) attention scale included -> attn uses exp2.
#define QSCALE 0.18033688011112042f  // 0.125 * log2(e)

// ---------- fused prep kernel ----------
__global__ __launch_bounds__(256) void prep_k(
    const float* __restrict__ x, short* __restrict__ xb,
    const float* __restrict__ Wqkv, short* __restrict__ WqkvT,
    const float* __restrict__ Wout, short* __restrict__ WoutT,
    float* __restrict__ cost, float* __restrict__ sint) {
  __shared__ float t[64][65];
  const int bx = blockIdx.x, tid = threadIdx.x;
  if (bx < 1024) {
    int base = bx * 4096 + tid * 4;
#pragma unroll
    for (int rep = 0; rep < 4; ++rep) {
      int i = base + rep * 1024;
      float4 v = *(const float4*)(x + i);
      *(short4*)(xb + i) = make_short4(tobf(v.x), tobf(v.y), tobf(v.z), tobf(v.w));
    }
  } else if (bx < 1664) {
    const float* in;
    short* out;
    int C, bb;
    if (bx < 1408) { in = Wqkv; out = WqkvT; C = 1536; bb = bx - 1024; }
    else           { in = Wout; out = WoutT; C = 1024; bb = bx - 1408; }
    const int R = 1024;
    int nc = C >> 6;
    int br = bb / nc, bc = bb % nc;
    int lr = tid >> 6, lc = tid & 63;
#pragma unroll
    for (int j = 0; j < 16; ++j) {
      int r = j * 4 + lr;
      t[r][lc] = in[(size_t)(br * 64 + r) * C + bc * 64 + lc];
    }
    __syncthreads();
#pragma unroll
    for (int j = 0; j < 16; ++j) {
      int r = j * 4 + lr;
      out[(size_t)(bc * 64 + r) * R + br * 64 + lc] = tobf(t[lc][r]);
    }
  } else {
    int t2 = (bx - 1664) * 256 + tid;  // < 65536
    int s = t2 >> 5, f = t2 & 31;
    float inv = __expf(-(float)f * (logf(50000.0f) / 32.0f));
    float a = (float)s * inv;
    cost[t2] = cosf(a);
    sint[t2] = sinf(a);
  }
}

// ---------- GEMM: C[M][N] = A[M][K](bf16) * Bt[N][K](bf16)^T + bias ----------
// 128x64 tiles. MODE 0: QKV proj; RoPE + q-prescale epilogue; q/k tiles ->
// bf16 qkvb; v tiles -> transposed vT directly (fused vtrans). MODE 1: f32 out.
template <int MODE>
__global__ __launch_bounds__(256) void gemm_k(
    const short* __restrict__ A, const short* __restrict__ Bt,
    const float* __restrict__ bias, void* __restrict__ Cout,
    short* __restrict__ vT,
    int M, int N, int K,
    const float* __restrict__ cost, const float* __restrict__ sint) {
  __shared__ short As[128 * 64];  // 16KB
  __shared__ short Bs[64 * 64];   // 8KB
  const int ntile = N >> 6;
  const int bm = blockIdx.x / ntile, bn = blockIdx.x % ntile;
  const int tid = threadIdx.x, w = tid >> 6, l = tid & 63;
  const int c = l & 15, g = l >> 4;
  const int m0 = bm * 128, n0 = bn * 64;

  f32x4 acc[2][4] = {};

  for (int k0 = 0; k0 < K; k0 += 64) {
#pragma unroll
    for (int j = 0; j < 4; ++j) {
      int rb = j * 32 + w * 8;
      int row = rb + (l >> 3);
      int colel = ((l & 7) ^ swz(row)) * 8;  // pre-swizzled source (rule #21)
      GLDS16(A + (size_t)(m0 + row) * K + k0 + colel, &As[rb * 64]);
      if (j < 2) GLDS16(Bt + (size_t)(n0 + row) * K + k0 + colel, &Bs[rb * 64]);
    }
    __syncthreads();
#pragma unroll
    for (int kk = 0; kk < 2; ++kk) {
      short8 af[2], bf[4];
#pragma unroll
      for (int mi = 0; mi < 2; ++mi) {
        int row = w * 32 + mi * 16 + c;
        af[mi] = *(const short8*)&As[row * 64 + ((kk * 4 + g) ^ swz(row)) * 8];
      }
#pragma unroll
      for (int ni = 0; ni < 4; ++ni) {
        int row = ni * 16 + c;
        bf[ni] = *(const short8*)&Bs[row * 64 + ((kk * 4 + g) ^ swz(row)) * 8];
      }
#pragma unroll
      for (int mi = 0; mi < 2; ++mi)
#pragma unroll
        for (int ni = 0; ni < 4; ++ni)
          acc[mi][ni] = __builtin_amdgcn_mfma_f32_16x16x32_bf16(af[mi], bf[ni], acc[mi][ni], 0, 0, 0);
    }
    __syncthreads();
  }

  if (MODE == 0 && n0 >= 1280) {
    // v region: write transposed directly to vT[b*4+hg][64 d][2048 s]
    const int hg = (n0 - 1280) >> 6;
#pragma unroll
    for (int mi = 0; mi < 2; ++mi) {
      int m0r = m0 + w * 32 + mi * 16 + g * 4;  // 4 consecutive rows
      int b = m0r >> 11, s = m0r & 2047;
#pragma unroll
      for (int ni = 0; ni < 4; ++ni) {
        int d = ni * 16 + c;
        float bs = bias[n0 + d];
        short4 o;
        o.x = tobf(acc[mi][ni][0] + bs);
        o.y = tobf(acc[mi][ni][1] + bs);
        o.z = tobf(acc[mi][ni][2] + bs);
        o.w = tobf(acc[mi][ni][3] + bs);
        *(short4*)&vT[(size_t)((b * 4 + hg) * 64 + d) * 2048 + s] = o;
      }
    }
    return;
  }

#pragma unroll
  for (int mi = 0; mi < 2; ++mi)
#pragma unroll
    for (int r = 0; r < 4; ++r) {
      int m = m0 + w * 32 + mi * 16 + g * 4 + r;
      int s = m & 2047;
#pragma unroll
      for (int ni = 0; ni < 4; ++ni) {
        int n = n0 + ni * 16 + c;
        float v = acc[mi][ni][r] + bias[n];
        if (MODE == 0) {
          // q or k region (n < 1280 guaranteed here): apply RoPE
          int d = n & 63, f = d & 31;
          float cs = cost[s * 32 + f], sn = sint[s * 32 + f];
          float partner = acc[mi][ni ^ 2][r] + bias[n ^ 32];
          v = (d < 32) ? (v * cs - partner * sn) : (v * cs + partner * sn);
          if (n < 1024) v *= QSCALE;  // q prescale (commutes with rotation)
          ((short*)Cout)[(size_t)m * N + n] = tobf(v);
        } else {
          ((float*)Cout)[(size_t)m * N + n] = v;
        }
      }
    }
}

// ---------- flash attention (causal, GQA), SPLIT-K, 4 blocks/CU ----------
// Grid 1024: block (bh, qt, half) processes half of q-tile qt's causal
// k-range (qt+1 tiles of 64), longest-first. LDS exactly 40KB (double-
// buffered K/V^T + per-wave P) -> 4 blocks/CU = 4 waves/SIMD (R14 measured
// 2-way concurrency as the limiter: 34 iters/CU at ~2500-cyc chains).
// Distance-1 prefetch issued at iter TOP (drain at bottom finds loads done).
// No-max log2-domain softmax; bf16 partial acco + f32 partial lrun.
__global__ __launch_bounds__(256) void attn_k(const short* __restrict__ qkv,
                                              const short* __restrict__ vT,
                                              short* __restrict__ pacc,
                                              float* __restrict__ plrun) {
  __shared__ short Ks2[2][64 * 64];  // 16KB
  __shared__ short Vt2[2][64 * 64];  // 16KB
  __shared__ short Ps[4][16 * 64];   // 8KB per-wave P tile

  const int bx = blockIdx.x;
  const int bh = bx & 31;
  const int idx = bx >> 5;           // 0..31
  const int qt = 15 - (idx >> 1);    // longest first (LPT)
  const int half = idx & 1;
  const int nkt = qt + 1;
  const int k0t = half * nkt;        // first k-tile of this half
  const int b = bh >> 4, h = bh & 15, hg = h >> 2;
  const int tid = threadIdx.x, w = tid >> 6, l = tid & 63;
  const int c = l & 15, g = l >> 4;
  const size_t rowbase = (size_t)(b * 2048) * 1536;

  // per-thread staging offsets (loop-invariant)
  const int i0row = w * 16 + (l >> 3);
  const int i1row = w * 16 + 8 + (l >> 3);
  const int c0 = ((l & 7) ^ swz(i0row)) * 8;
  const int c1 = ((l & 7) ^ swz(i1row)) * 8;
  const size_t k0off = (size_t)i0row * 1536 + c0;
  const size_t k1off = (size_t)i1row * 1536 + c1;
  const size_t v0off = (size_t)i0row * 2048 + c0;
  const size_t v1off = (size_t)i1row * 2048 + c1;
  const int lds0 = (w * 16) * 64;
  const int lds1 = (w * 16 + 8) * 64;
  const short* kbase = qkv + rowbase + 1024 + hg * 64;
  const short* vbase_p = vT + (size_t)((b * 4 + hg) * 64) * 2048;

  // Q fragments direct from global: q = qt*128 + w*32 + set*16 + c
  short8 aq[2][2];
#pragma unroll
  for (int set = 0; set < 2; ++set)
#pragma unroll
    for (int kk = 0; kk < 2; ++kk)
      aq[set][kk] = *(const short8*)(qkv + rowbase +
          (size_t)(qt * 128 + w * 32 + set * 16 + c) * 1536 + h * 64 + kk * 32 + g * 8);

  // ---- prologue: stage tile k0t into buf 0 ----
  GLDS16(kbase + (size_t)k0t * 98304 + k0off, &Ks2[0][lds0]);
  GLDS16(kbase + (size_t)k0t * 98304 + k1off, &Ks2[0][lds1]);
  GLDS16(vbase_p + k0t * 64 + v0off, &Vt2[0][lds0]);
  GLDS16(vbase_p + k0t * 64 + v1off, &Vt2[0][lds1]);
  asm volatile("s_waitcnt vmcnt(0)" ::: "memory");
  __builtin_amdgcn_s_barrier();
  __builtin_amdgcn_sched_barrier(0);

  f32x4 acco[2][4] = {};
  float lrun[2] = {0.f, 0.f};
  short* Pw = &Ps[w][0];

  for (int i = 0; i < nkt; ++i) {
    const int cur = i & 1, nxt = cur ^ 1;
    const int kt = k0t + i;
    if (i + 1 < nkt) {  // issue next tile at iter TOP (hides under compute)
      GLDS16(kbase + (size_t)(kt + 1) * 98304 + k0off, &Ks2[nxt][lds0]);
      GLDS16(kbase + (size_t)(kt + 1) * 98304 + k1off, &Ks2[nxt][lds1]);
      GLDS16(vbase_p + (kt + 1) * 64 + v0off, &Vt2[nxt][lds0]);
      GLDS16(vbase_p + (kt + 1) * 64 + v1off, &Vt2[nxt][lds1]);
    }

    // K fragment reads (shared by both q-sets)
    short8 bk[2][4];
#pragma unroll
    for (int kk = 0; kk < 2; ++kk)
#pragma unroll
      for (int nb = 0; nb < 4; ++nb) {
        int row = nb * 16 + c;
        bk[kk][nb] = *(const short8*)&Ks2[cur][row * 64 + ((kk * 4 + g) ^ swz(row)) * 8];
      }

    // QK both sets: S^T = K * Q^T
    f32x4 sfr[2][4] = {};
    __builtin_amdgcn_s_setprio(1);
#pragma unroll
    for (int set = 0; set < 2; ++set)
#pragma unroll
      for (int kk = 0; kk < 2; ++kk)
#pragma unroll
        for (int nb = 0; nb < 4; ++nb)
          sfr[set][nb] = __builtin_amdgcn_mfma_f32_16x16x32_bf16(
              bk[kk][nb], aq[set][kk], sfr[set][nb], 0, 0, 0);
    __builtin_amdgcn_s_setprio(0);

    // V fragment reads (bk now dead)
    short8 bv[2][4];
#pragma unroll
    for (int kk = 0; kk < 2; ++kk)
#pragma unroll
      for (int nb = 0; nb < 4; ++nb) {
        int row = nb * 16 + c;
        bv[kk][nb] = *(const short8*)&Vt2[cur][row * 64 + ((kk * 4 + g) ^ swz(row)) * 8];
      }

    // causal mask: only tiles intersecting the diagonal band
    if (kt >= 2 * qt) {
#pragma unroll
      for (int set = 0; set < 2; ++set) {
        int qg = qt * 128 + w * 32 + set * 16 + c;
#pragma unroll
        for (int nb = 0; nb < 4; ++nb)
#pragma unroll
          for (int r = 0; r < 4; ++r)
            if (kt * 64 + nb * 16 + g * 4 + r > qg) sfr[set][nb][r] = -1e30f;
      }
    }

    // per set: NO-MAX softmax (log2 domain), P bounce, PV
#pragma unroll
    for (int set = 0; set < 2; ++set) {
      float rs = 0.f;
#pragma unroll
      for (int nb = 0; nb < 4; ++nb)
#pragma unroll
        for (int r = 0; r < 4; ++r) {
          float p = exp2f(sfr[set][nb][r]);
          sfr[set][nb][r] = p;
          rs += p;
        }
      rs += __shfl_xor(rs, 16, 64);
      rs += __shfl_xor(rs, 32, 64);
      lrun[set] += rs;

#pragma unroll
      for (int nb = 0; nb < 4; ++nb) {
        short4 pq;
        pq.x = tobf(sfr[set][nb][0]);
        pq.y = tobf(sfr[set][nb][1]);
        pq.z = tobf(sfr[set][nb][2]);
        pq.w = tobf(sfr[set][nb][3]);
        int pslot = (nb * 2 + (g >> 1)) ^ swz(c);
        *(short4*)&Pw[c * 64 + pslot * 8 + (g & 1) * 4] = pq;
      }

      __builtin_amdgcn_s_setprio(1);
#pragma unroll
      for (int kk = 0; kk < 2; ++kk) {
        short8 ap = *(const short8*)&Pw[c * 64 + (((kk * 4 + g) ^ swz(c)) * 8)];
#pragma unroll
        for (int nb = 0; nb < 4; ++nb)
          acco[set][nb] = __builtin_amdgcn_mfma_f32_16x16x32_bf16(ap, bv[kk][nb], acco[set][nb], 0, 0, 0);
      }
      __builtin_amdgcn_s_setprio(0);
    }

    // drain (loads were issued at iter top -> already complete) + barrier
    asm volatile("s_waitcnt vmcnt(0)" ::: "memory");
    __builtin_amdgcn_s_barrier();
    __builtin_amdgcn_sched_barrier(0);
  }

  // store partial: pacc[bh][qt][half][128][64] bf16, plrun[bh][qt][half][128]
  {
    size_t pb = ((size_t)((bh * 16 + qt) * 2 + half)) * 8192;
#pragma unroll
    for (int set = 0; set < 2; ++set) {
#pragma unroll
      for (int nb = 0; nb < 4; ++nb)
#pragma unroll
        for (int r = 0; r < 4; ++r) {
          int row = w * 32 + set * 16 + g * 4 + r;
          pacc[pb + row * 64 + nb * 16 + c] = tobf(acco[set][nb][r]);
        }
      if (g == 0)
        plrun[((bh * 16 + qt) * 2 + half) * 128 + w * 32 + set * 16 + c] = lrun[set];
    }
  }
}

// ---------- combine: attnb = (pacc[h0] + pacc[h1]) / (lrun[h0] + lrun[h1]) ----------
__global__ __launch_bounds__(256) void combine_k(const short* __restrict__ pacc,
                                                 const float* __restrict__ plrun,
                                                 short* __restrict__ attnb) {
  int e = blockIdx.x * 256 + threadIdx.x;  // 0..524287
  int d8 = e & 7;
  int t = e >> 3;
  int row = t & 127;
  int t2 = t >> 7;
  int qt = t2 & 15;
  int bh = t2 >> 4;
  size_t pb = (size_t)((bh * 16 + qt) * 2) * 8192 + row * 64 + d8 * 8;
  short8 a0 = *(const short8*)(pacc + pb);
  short8 a1 = *(const short8*)(pacc + pb + 8192);
  float l = plrun[(bh * 16 + qt) * 2 * 128 + row] +
            plrun[((bh * 16 + qt) * 2 + 1) * 128 + row];
  float li = 1.0f / l;
  int b = bh >> 4, h = bh & 15;
  int m = b * 2048 + qt * 128 + row;
  int n = h * 64 + d8 * 8;
  short8 o;
#pragma unroll
  for (int k = 0; k < 8; ++k) o[k] = tobf((frombf(a0[k]) + frombf(a1[k])) * li);
  *(short8*)(attnb + (size_t)m * 1024 + n) = o;
}

// ---------- launch ----------
extern "C" void kernel_launch(void* const* d_in, const int* in_sizes, int n_in,
                              void* d_out, int out_size, void* d_ws, size_t ws_size,
                              hipStream_t stream) {
  const float* x    = (const float*)d_in[0];
  const float* Wqkv = (const float*)d_in[1];
  const float* bqkv = (const float*)d_in[2];
  const float* Wout = (const float*)d_in[3];
  const float* bout = (const float*)d_in[4];

  char* ws = (char*)d_ws;
  short* xb    = (short*)ws; ws += 8388608;    // x bf16 [4096][1024]
  short* WqkvT = (short*)ws; ws += 3145728;    // [1536][1024] bf16
  short* WoutT = (short*)ws; ws += 2097152;    // [1024][1024] bf16
  short* qkvb  = (short*)ws; ws += 12582912;   // [4096][1536] bf16 (q/k post-RoPE)
  short* attnb = (short*)ws; ws += 8388608;    // [4096][1024] bf16
  short* vTb   = (short*)ws; ws += 2097152;    // [8][64][2048] bf16 (V transposed)
  float* cost  = (float*)ws; ws += 262144;     // [2048][32]
  float* sint  = (float*)ws; ws += 262144;
  short* pacc  = (short*)ws; ws += 16777216;   // [32][16][2][128][64] bf16 partial acco
  float* plrun = (float*)ws; ws += 524288;     // [32][16][2][128] f32 partial lrun

  prep_k<<<1920, 256, 0, stream>>>(x, xb, Wqkv, WqkvT, Wout, WoutT, cost, sint);
  gemm_k<0><<<768, 256, 0, stream>>>(xb, WqkvT, bqkv, (void*)qkvb, vTb, 4096, 1536, 1024, cost, sint);
  attn_k<<<1024, 256, 0, stream>>>(qkvb, vTb, pacc, plrun);
  combine_k<<<2048, 256, 0, stream>>>(pacc, plrun, attnb);
  gemm_k<1><<<512, 256, 0, stream>>>(attnb, WoutT, bout, d_out, nullptr, 4096, 1024, 1024, cost, sint);
}